// Round 1
// 367.365 us; speedup vs baseline: 1.0177x; 1.0177x over previous
//
#include <hip/hip_runtime.h>
#include <math.h>

#define B_TOT 3072
#define PIX   12288   // 64*64*3 elements per batch image
#define BM    8       // batches per block in kernel A (amortizes weight stream)

typedef float v2f __attribute__((ext_vector_type(2)));

// ---------------------------------------------------------------------------
// Kernel A (v2): one block per BM=8 batches. Previous version streamed the
// full 294 KB of w1+w2 once PER BATCH (3072x) with 48B-lane-stride dwordx4
// loads (~48 line-transactions per instr) -> ~42M line requests ~ 75 us of
// VMEM issue. Now each weight chunk (6 float4 in registers) is reused across
// 8 batches: weight instr/transaction count and L2 bytes / 8. x loads stay
// fully coalesced. Numerics identical in structure: fp32 per-thread partials
// (48 products per batch per thread, same as v1), fp32 wave shuffles, fp64
// only for the cross-wave combine + 2x2 inversion (kappa(G) amplification).
// ---------------------------------------------------------------------------
__global__ __launch_bounds__(256) void compute_M_kernel(
    const float* __restrict__ x, const float* __restrict__ w1,
    const float* __restrict__ b1, const float* __restrict__ w2,
    const float* __restrict__ b2, float* __restrict__ Mout) {
  const int b0 = blockIdx.x * BM;
  const float4* __restrict__ w14 = (const float4*)w1;
  const float4* __restrict__ w24 = (const float4*)w2;
  const float4* __restrict__ xb4 = (const float4*)(x + (size_t)b0 * PIX);

  float acc[BM][6];
  #pragma unroll
  for (int b = 0; b < BM; ++b)
    #pragma unroll
    for (int f = 0; f < 6; ++f) acc[b][f] = 0.f;

  // 12 chunks of 256 float4 over the 3072 x-float4s of each batch.
  for (int it = 0; it < PIX / 4 / 256; ++it) {
    const int i4 = threadIdx.x + it * 256;
    // weights for this thread's 4 x-floats: group layout g[e*3+f]
    float4 a0 = w14[i4 * 3 + 0], a1 = w14[i4 * 3 + 1], a2 = w14[i4 * 3 + 2];
    float4 c0 = w24[i4 * 3 + 0], c1 = w24[i4 * 3 + 1], c2 = w24[i4 * 3 + 2];
    #pragma unroll
    for (int b = 0; b < BM; ++b) {
      float4 xv = xb4[(size_t)b * (PIX / 4) + i4];
      acc[b][0] += xv.x * a0.x + xv.y * a0.w + xv.z * a1.z + xv.w * a2.y;
      acc[b][1] += xv.x * a0.y + xv.y * a1.x + xv.z * a1.w + xv.w * a2.z;
      acc[b][2] += xv.x * a0.z + xv.y * a1.y + xv.z * a2.x + xv.w * a2.w;
      acc[b][3] += xv.x * c0.x + xv.y * c0.w + xv.z * c1.z + xv.w * c2.y;
      acc[b][4] += xv.x * c0.y + xv.y * c1.x + xv.z * c1.w + xv.w * c2.z;
      acc[b][5] += xv.x * c0.z + xv.y * c1.y + xv.z * c2.x + xv.w * c2.w;
    }
  }

  // wave-level fp32 reduction of all 48 partials
  #pragma unroll
  for (int b = 0; b < BM; ++b)
    #pragma unroll
    for (int f = 0; f < 6; ++f)
      #pragma unroll
      for (int off = 32; off > 0; off >>= 1)
        acc[b][f] += __shfl_down(acc[b][f], off, 64);

  __shared__ float wred[4][BM][6];
  const int wave = threadIdx.x >> 6, lane = threadIdx.x & 63;
  if (lane == 0) {
    #pragma unroll
    for (int b = 0; b < BM; ++b)
      #pragma unroll
      for (int f = 0; f < 6; ++f) wred[wave][b][f] = acc[b][f];
  }
  __syncthreads();

  // one thread per batch: fp64 combine + L1 norm + G inverse -> M = Ginv V^T
  if (threadIdx.x < BM) {
    const int b = threadIdx.x;
    double v[3][2];   // v[c][k]
    for (int c = 0; c < 3; ++c) {
      v[c][0] = (double)wred[0][b][c] + (double)wred[1][b][c] +
                (double)wred[2][b][c] + (double)wred[3][b][c] + (double)b1[c];
      v[c][1] = (double)wred[0][b][3 + c] + (double)wred[1][b][3 + c] +
                (double)wred[2][b][3 + c] + (double)wred[3][b][3 + c] +
                (double)b2[c];
    }
    for (int k = 0; k < 2; ++k) {
      double l1 = 1e-6 + fabs(v[0][k]) + fabs(v[1][k]) + fabs(v[2][k]);
      for (int c = 0; c < 3; ++c) v[c][k] /= l1;
    }
    double G00 = 0, G01 = 0, G11 = 0;
    for (int c = 0; c < 3; ++c) {
      G00 += v[c][0] * v[c][0];
      G01 += v[c][0] * v[c][1];
      G11 += v[c][1] * v[c][1];
    }
    double det = G00 * G11 - G01 * G01;
    double i00 = G11 / det, i01 = -G01 / det, i11 = G00 / det;
    float* Mo = Mout + (size_t)(b0 + b) * 6;
    for (int c = 0; c < 3; ++c) {
      Mo[0 * 3 + c] = (float)(i00 * v[c][0] + i01 * v[c][1]);
      Mo[1 * 3 + c] = (float)(i01 * v[c][0] + i11 * v[c][1]);
    }
  }
}

// ---------------------------------------------------------------------------
// Kernel B: one block (256 threads) per output image b2 (2048 blocks).
//   z flat m = b2*12288 + ml -> (b = m>>13, n = (m&8191)>>1, k = m&1);
//   z = M[b][k] . x[b,n,0..2].
//   Phase 1: groups of 4 pixels (8 z) per thread-iter: 3 float4 x-loads +
//   2 float4 LDS writes. Group base n0 % 4 == 0 (16B aligned) and a group
//   never straddles a batch boundary (8192 % 8 == 0).
//   Phase 2: 48 active lanes/wave own one column (w = wave*16 + lane/3,
//   c = lane%3) so the group-of-3 lane transpose stays inside one wave.
//   Column (64 rows) + 16 antisymmetric taps live in registers. Per h:
//   2 shuffles re-pack (rec,hil) of the 3-lane group into contiguous
//   float2 per lane -> one nontemporal dwordx2 store; a wave writes 384 B
//   contiguous, every 64B line fully dirty immediately (no partial-line
//   RMW; R1 showed 1.96x write amplification from split-channel writes).
//   [UNCHANGED this round — isolates kernel A's delta.]
// ---------------------------------------------------------------------------
__global__ __launch_bounds__(256) void z_hilbert_kernel(
    const float* __restrict__ x, const float* __restrict__ M,
    float* __restrict__ out) {
  const int b2 = blockIdx.x;
  __shared__ __align__(16) float rec[PIX];   // 48 KB
  __shared__ float Ms[12];
  const size_t zbase = (size_t)b2 * PIX;
  const int b_lo = (int)(zbase >> 13);
  if (threadIdx.x < 12) {
    int bb = b_lo + (int)(threadIdx.x / 6);
    float mv = 0.f;
    if (bb < B_TOT) mv = M[(size_t)bb * 6 + (threadIdx.x % 6)];
    Ms[threadIdx.x] = mv;
  }
  __syncthreads();
  float* outb = out + (size_t)b2 * 24576;   // (64,64,6) per image

  // Phase 1: 1536 groups of 4 pixels; 6 iterations per thread.
  for (int g = threadIdx.x; g < PIX / 8; g += 256) {
    int ml = g << 3;
    size_t m = zbase + (size_t)ml;
    int b = (int)(m >> 13);
    int n0 = (int)((m & 8191) >> 1);        // n0 % 4 == 0
    int wb = (b - b_lo) * 6;
    float m00 = Ms[wb + 0], m01 = Ms[wb + 1], m02 = Ms[wb + 2];
    float m10 = Ms[wb + 3], m11 = Ms[wb + 4], m12 = Ms[wb + 5];
    const float4* xp = (const float4*)(x + (size_t)b * PIX + (size_t)n0 * 3);
    float4 p0 = xp[0], p1 = xp[1], p2 = xp[2];
    float4 o0, o1;
    o0.x = m00 * p0.x + m01 * p0.y + m02 * p0.z;
    o0.y = m10 * p0.x + m11 * p0.y + m12 * p0.z;
    o0.z = m00 * p0.w + m01 * p1.x + m02 * p1.y;
    o0.w = m10 * p0.w + m11 * p1.x + m12 * p1.y;
    o1.x = m00 * p1.z + m01 * p1.w + m02 * p2.x;
    o1.y = m10 * p1.z + m11 * p1.w + m12 * p2.x;
    o1.z = m00 * p2.y + m01 * p2.z + m02 * p2.w;
    o1.w = m10 * p2.y + m11 * p2.z + m12 * p2.w;
    float4* rp = (float4*)&rec[ml];
    rp[0] = o0;
    rp[1] = o1;
  }
  __syncthreads();

  // Phase 2
  const int wave = threadIdx.x >> 6, lane = threadIdx.x & 63;
  if (lane < 48) {
    const int w = wave * 16 + lane / 3;
    const int c = lane % 3;
    const int col = w * 3 + c;
    float gc[16];
    #pragma unroll
    for (int jj = 0; jj < 16; ++jj) {
      float ang = 3.14159265358979323846f * (float)(2 * jj + 1) / 64.0f;
      gc[jj] = 0.03125f * cosf(ang) / sinf(ang);   // (1/32)cot(pi d/64), odd d
    }
    float v[64];
    #pragma unroll
    for (int h = 0; h < 64; ++h) v[h] = rec[h * 192 + col];
    float* oc = outb + w * 6 + c * 2;   // this lane's float2 slot per pixel
    #pragma unroll
    for (int h = 0; h < 64; ++h) {
      float acc = 0.f;
      #pragma unroll
      for (int jj = 0; jj < 16; ++jj) {
        int d = 2 * jj + 1;
        acc += gc[jj] * (v[(h - d) & 63] - v[(h + d) & 63]);
      }
      float r = v[h];
      // lane transpose within group of 3: pixel = [r0,r1,r2,a0,a1,a2]
      float s1 = __shfl(r, lane + 1, 64);    // r of next lane (c+1)
      float s2 = __shfl(acc, lane - 1, 64);  // a of prev lane (c-1)
      v2f st;
      st.x = (c == 0) ? r : ((c == 1) ? s1 : s2);
      st.y = (c == 0) ? s1 : ((c == 1) ? s2 : acc);
      __builtin_nontemporal_store(st, (v2f*)(oc + (size_t)h * 384));
    }
  }
}

extern "C" void kernel_launch(void* const* d_in, const int* in_sizes, int n_in,
                              void* d_out, int out_size, void* d_ws, size_t ws_size,
                              hipStream_t stream) {
  const float* x  = (const float*)d_in[0];   // (3072,64,64,3)
  const float* w1 = (const float*)d_in[1];   // (64,64,3,3)
  const float* b1 = (const float*)d_in[2];   // (3,)
  const float* w2 = (const float*)d_in[3];   // (64,64,3,3)
  const float* b2 = (const float*)d_in[4];   // (3,)
  float* out = (float*)d_out;                // (2048,64,64,6)
  float* M = (float*)d_ws;                   // 3072*6 floats

  compute_M_kernel<<<B_TOT / BM, 256, 0, stream>>>(x, w1, b1, w2, b2, M);
  z_hilbert_kernel<<<2048, 256, 0, stream>>>(x, M, out);
}

// Round 3
// 343.859 us; speedup vs baseline: 1.0873x; 1.0684x over previous
//
#include <hip/hip_runtime.h>
#include <math.h>

#define B_TOT 3072
#define PIX   12288   // 64*64*3 elements per batch image
#define BM    4       // batches per block in kernel A

typedef float v2f __attribute__((ext_vector_type(2)));

// ---------------------------------------------------------------------------
// Kernel A (v3): BM=4, grid 768. R1 post-mortem: BM=8 (grid 384) dropped
// occupancy to 1.5 blocks/CU (6 waves/CU) — if A was latency-bound there,
// the 8x transaction cut was given back. BM=4 keeps round-0's 12 waves/CU
// (3 blocks/CU x 4 waves) with a 4x weight-transaction cut vs round 0:
// strictly dominates both prior configs under either bottleneck theory.
// #pragma unroll 2 keeps two chunks of loads in flight (~26 live float4
// ~ 150 VGPR < 170 budget for 3 waves/SIMD).
// Numerics unchanged: fp32 per-thread partials, fp32 wave shuffles, fp64
// only for cross-wave combine + L1 norm + 2x2 inversion.
// [R2 was an infra failure (container acquisition); identical resubmit.]
// ---------------------------------------------------------------------------
__global__ __launch_bounds__(256) void compute_M_kernel(
    const float* __restrict__ x, const float* __restrict__ w1,
    const float* __restrict__ b1, const float* __restrict__ w2,
    const float* __restrict__ b2, float* __restrict__ Mout) {
  const int b0 = blockIdx.x * BM;
  const float4* __restrict__ w14 = (const float4*)w1;
  const float4* __restrict__ w24 = (const float4*)w2;
  const float4* __restrict__ xb4 = (const float4*)(x + (size_t)b0 * PIX);

  float acc[BM][6];
  #pragma unroll
  for (int b = 0; b < BM; ++b)
    #pragma unroll
    for (int f = 0; f < 6; ++f) acc[b][f] = 0.f;

  // 12 chunks of 256 float4 over the 3072 x-float4s of each batch.
  #pragma unroll 2
  for (int it = 0; it < PIX / 4 / 256; ++it) {
    const int i4 = threadIdx.x + it * 256;
    // weights for this thread's 4 x-floats: group layout g[e*3+f]
    float4 a0 = w14[i4 * 3 + 0], a1 = w14[i4 * 3 + 1], a2 = w14[i4 * 3 + 2];
    float4 c0 = w24[i4 * 3 + 0], c1 = w24[i4 * 3 + 1], c2 = w24[i4 * 3 + 2];
    #pragma unroll
    for (int b = 0; b < BM; ++b) {
      float4 xv = xb4[(size_t)b * (PIX / 4) + i4];
      acc[b][0] += xv.x * a0.x + xv.y * a0.w + xv.z * a1.z + xv.w * a2.y;
      acc[b][1] += xv.x * a0.y + xv.y * a1.x + xv.z * a1.w + xv.w * a2.z;
      acc[b][2] += xv.x * a0.z + xv.y * a1.y + xv.z * a2.x + xv.w * a2.w;
      acc[b][3] += xv.x * c0.x + xv.y * c0.w + xv.z * c1.z + xv.w * c2.y;
      acc[b][4] += xv.x * c0.y + xv.y * c1.x + xv.z * c1.w + xv.w * c2.z;
      acc[b][5] += xv.x * c0.z + xv.y * c1.y + xv.z * c2.x + xv.w * c2.w;
    }
  }

  // wave-level fp32 reduction of all 24 partials
  #pragma unroll
  for (int b = 0; b < BM; ++b)
    #pragma unroll
    for (int f = 0; f < 6; ++f)
      #pragma unroll
      for (int off = 32; off > 0; off >>= 1)
        acc[b][f] += __shfl_down(acc[b][f], off, 64);

  __shared__ float wred[4][BM][6];
  const int wave = threadIdx.x >> 6, lane = threadIdx.x & 63;
  if (lane == 0) {
    #pragma unroll
    for (int b = 0; b < BM; ++b)
      #pragma unroll
      for (int f = 0; f < 6; ++f) wred[wave][b][f] = acc[b][f];
  }
  __syncthreads();

  // one thread per batch: fp64 combine + L1 norm + G inverse -> M = Ginv V^T
  if (threadIdx.x < BM) {
    const int b = threadIdx.x;
    double v[3][2];   // v[c][k]
    for (int c = 0; c < 3; ++c) {
      v[c][0] = (double)wred[0][b][c] + (double)wred[1][b][c] +
                (double)wred[2][b][c] + (double)wred[3][b][c] + (double)b1[c];
      v[c][1] = (double)wred[0][b][3 + c] + (double)wred[1][b][3 + c] +
                (double)wred[2][b][3 + c] + (double)wred[3][b][3 + c] +
                (double)b2[c];
    }
    for (int k = 0; k < 2; ++k) {
      double l1 = 1e-6 + fabs(v[0][k]) + fabs(v[1][k]) + fabs(v[2][k]);
      for (int c = 0; c < 3; ++c) v[c][k] /= l1;
    }
    double G00 = 0, G01 = 0, G11 = 0;
    for (int c = 0; c < 3; ++c) {
      G00 += v[c][0] * v[c][0];
      G01 += v[c][0] * v[c][1];
      G11 += v[c][1] * v[c][1];
    }
    double det = G00 * G11 - G01 * G01;
    double i00 = G11 / det, i01 = -G01 / det, i11 = G00 / det;
    float* Mo = Mout + (size_t)(b0 + b) * 6;
    for (int c = 0; c < 3; ++c) {
      Mo[0 * 3 + c] = (float)(i00 * v[c][0] + i01 * v[c][1]);
      Mo[1 * 3 + c] = (float)(i01 * v[c][0] + i11 * v[c][1]);
    }
  }
}

// ---------------------------------------------------------------------------
// Kernel B: one block (256 threads) per output image b2 (2048 blocks).
//   z flat m = b2*12288 + ml -> (b = m>>13, n = (m&8191)>>1, k = m&1);
//   z = M[b][k] . x[b,n,0..2].
//   Phase 1: groups of 4 pixels (8 z) per thread-iter: 3 float4 x-loads +
//   2 float4 LDS writes. Exact-trip-count loop (6 iters), fully unrolled so
//   all 18 x-loads issue before the first LDS write (deeper vmcnt pipeline).
//   Phase 2: 48 active lanes/wave own one column (w = wave*16 + lane/3,
//   c = lane%3); column (64 rows) + 16 antisymmetric taps in registers.
//   Per h: 2 shuffles re-pack (rec,hil) of the 3-lane group into one
//   contiguous float2 per lane -> nontemporal dwordx2; a wave writes 384 B
//   contiguous (no partial-line RMW).
// ---------------------------------------------------------------------------
__global__ __launch_bounds__(256) void z_hilbert_kernel(
    const float* __restrict__ x, const float* __restrict__ M,
    float* __restrict__ out) {
  const int b2 = blockIdx.x;
  __shared__ __align__(16) float rec[PIX];   // 48 KB
  __shared__ float Ms[12];
  const size_t zbase = (size_t)b2 * PIX;
  const int b_lo = (int)(zbase >> 13);
  if (threadIdx.x < 12) {
    int bb = b_lo + (int)(threadIdx.x / 6);
    float mv = 0.f;
    if (bb < B_TOT) mv = M[(size_t)bb * 6 + (threadIdx.x % 6)];
    Ms[threadIdx.x] = mv;
  }
  __syncthreads();
  float* outb = out + (size_t)b2 * 24576;   // (64,64,6) per image

  // Phase 1: 1536 groups of 4 pixels; exactly 6 iterations per thread.
  #pragma unroll
  for (int it = 0; it < 6; ++it) {
    int g = threadIdx.x + it * 256;
    int ml = g << 3;
    size_t m = zbase + (size_t)ml;
    int b = (int)(m >> 13);
    int n0 = (int)((m & 8191) >> 1);        // n0 % 4 == 0
    int wb = (b - b_lo) * 6;
    float m00 = Ms[wb + 0], m01 = Ms[wb + 1], m02 = Ms[wb + 2];
    float m10 = Ms[wb + 3], m11 = Ms[wb + 4], m12 = Ms[wb + 5];
    const float4* xp = (const float4*)(x + (size_t)b * PIX + (size_t)n0 * 3);
    float4 p0 = xp[0], p1 = xp[1], p2 = xp[2];
    float4 o0, o1;
    o0.x = m00 * p0.x + m01 * p0.y + m02 * p0.z;
    o0.y = m10 * p0.x + m11 * p0.y + m12 * p0.z;
    o0.z = m00 * p0.w + m01 * p1.x + m02 * p1.y;
    o0.w = m10 * p0.w + m11 * p1.x + m12 * p1.y;
    o1.x = m00 * p1.z + m01 * p1.w + m02 * p2.x;
    o1.y = m10 * p1.z + m11 * p1.w + m12 * p2.x;
    o1.z = m00 * p2.y + m01 * p2.z + m02 * p2.w;
    o1.w = m10 * p2.y + m11 * p2.z + m12 * p2.w;
    float4* rp = (float4*)&rec[ml];
    rp[0] = o0;
    rp[1] = o1;
  }
  __syncthreads();

  // Phase 2
  const int wave = threadIdx.x >> 6, lane = threadIdx.x & 63;
  if (lane < 48) {
    const int w = wave * 16 + lane / 3;
    const int c = lane % 3;
    const int col = w * 3 + c;
    float gc[16];
    #pragma unroll
    for (int jj = 0; jj < 16; ++jj) {
      float ang = 3.14159265358979323846f * (float)(2 * jj + 1) / 64.0f;
      gc[jj] = 0.03125f * cosf(ang) / sinf(ang);   // (1/32)cot(pi d/64), odd d
    }
    float v[64];
    #pragma unroll
    for (int h = 0; h < 64; ++h) v[h] = rec[h * 192 + col];
    float* oc = outb + w * 6 + c * 2;   // this lane's float2 slot per pixel
    #pragma unroll
    for (int h = 0; h < 64; ++h) {
      float acc = 0.f;
      #pragma unroll
      for (int jj = 0; jj < 16; ++jj) {
        int d = 2 * jj + 1;
        acc += gc[jj] * (v[(h - d) & 63] - v[(h + d) & 63]);
      }
      float r = v[h];
      // lane transpose within group of 3: pixel = [r0,r1,r2,a0,a1,a2]
      float s1 = __shfl(r, lane + 1, 64);    // r of next lane (c+1)
      float s2 = __shfl(acc, lane - 1, 64);  // a of prev lane (c-1)
      v2f st;
      st.x = (c == 0) ? r : ((c == 1) ? s1 : s2);
      st.y = (c == 0) ? s1 : ((c == 1) ? s2 : acc);
      __builtin_nontemporal_store(st, (v2f*)(oc + (size_t)h * 384));
    }
  }
}

extern "C" void kernel_launch(void* const* d_in, const int* in_sizes, int n_in,
                              void* d_out, int out_size, void* d_ws, size_t ws_size,
                              hipStream_t stream) {
  const float* x  = (const float*)d_in[0];   // (3072,64,64,3)
  const float* w1 = (const float*)d_in[1];   // (64,64,3,3)
  const float* b1 = (const float*)d_in[2];   // (3,)
  const float* w2 = (const float*)d_in[3];   // (64,64,3,3)
  const float* b2 = (const float*)d_in[4];   // (3,)
  float* out = (float*)d_out;                // (2048,64,64,6)
  float* M = (float*)d_ws;                   // 3072*6 floats

  compute_M_kernel<<<B_TOT / BM, 256, 0, stream>>>(x, w1, b1, w2, b2, M);
  z_hilbert_kernel<<<2048, 256, 0, stream>>>(x, M, out);
}